// Round 6
// baseline (230.846 us; speedup 1.0000x reference)
//
#include <hip/hip_runtime.h>

// out[r][c] = x[r][c] * diag[c]
// x: 16384 x 2048 fp32, diag: 2048 fp32. Memory-bound broadcast multiply.
//
// v6: same 32 KiB contiguous block tiles as v4/v5, but the 8-deep read
// burst is pinned with an asm liveness barrier. History:
//  - v4 (#pragma unroll loops):      VGPR=28 -> compiler re-paired load/store.
//  - v5 (sched_barrier(0)):          VGPR=24 -> loads sank past the barrier
//    anyway (middle-end, not MIsched). MLP never actually tested.
//  - v6: empty `asm volatile` with "+v" on all 8 values: the asm USES all
//    eight registers, so all 8 global_load_dwordx4 must issue before it and
//    be simultaneously live. VGPR_Count >= 48 is the proof the burst held.
using f4 = __attribute__((ext_vector_type(4))) float;

constexpr int BLOCK = 256;
constexpr int K     = 8;             // float4s per thread
constexpr int TILE  = BLOCK * K;     // 2048 float4s = 4 rows = 32 KiB

__global__ __launch_bounds__(BLOCK) void DiagonalDense_kernel(
    const f4* __restrict__ x,
    const f4* __restrict__ diag,
    f4* __restrict__ out) {
    const int t    = threadIdx.x;
    const int base = blockIdx.x * TILE + t;

    // (base + j*BLOCK) & 511 == (j&1)*256 + t  (tile base is 2048-aligned)
    const f4 dv0 = diag[t];          // even j
    const f4 dv1 = diag[t + 256];    // odd j

    // ---- load cluster: 8 independent reads ----
    f4 r0 = x[base + 0 * BLOCK];
    f4 r1 = x[base + 1 * BLOCK];
    f4 r2 = x[base + 2 * BLOCK];
    f4 r3 = x[base + 3 * BLOCK];
    f4 r4 = x[base + 4 * BLOCK];
    f4 r5 = x[base + 5 * BLOCK];
    f4 r6 = x[base + 6 * BLOCK];
    f4 r7 = x[base + 7 * BLOCK];

    // Liveness pin: all 8 values must be materialized in VGPRs here.
    // Loads cannot sink below this; stores cannot start before it.
    asm volatile("" : "+v"(r0), "+v"(r1), "+v"(r2), "+v"(r3),
                      "+v"(r4), "+v"(r5), "+v"(r6), "+v"(r7));

    // ---- mul + store cluster ----
    out[base + 0 * BLOCK] = r0 * dv0;
    out[base + 1 * BLOCK] = r1 * dv1;
    out[base + 2 * BLOCK] = r2 * dv0;
    out[base + 3 * BLOCK] = r3 * dv1;
    out[base + 4 * BLOCK] = r4 * dv0;
    out[base + 5 * BLOCK] = r5 * dv1;
    out[base + 6 * BLOCK] = r6 * dv0;
    out[base + 7 * BLOCK] = r7 * dv1;
}

extern "C" void kernel_launch(void* const* d_in, const int* in_sizes, int n_in,
                              void* d_out, int out_size, void* d_ws, size_t ws_size,
                              hipStream_t stream) {
    const f4* x    = (const f4*)d_in[0];   // 16384*2048 fp32
    const f4* diag = (const f4*)d_in[1];   // 2048 fp32
    f4* out        = (f4*)d_out;

    const int n  = out_size;       // 33,554,432 floats
    const int n4 = n / 4;          // 8,388,608 float4s
    const int grid = n4 / TILE;    // 4096 blocks, exact (no remainder)

    DiagonalDense_kernel<<<grid, BLOCK, 0, stream>>>(x, diag, out);
}

// Round 7
// 219.082 us; speedup vs baseline: 1.0537x; 1.0537x over previous
//
#include <hip/hip_runtime.h>

// out[r][c] = x[r][c] * diag[c]
// x: 16384 x 2048 fp32, diag: 2048 fp32. Memory-bound broadcast multiply.
//
// v7: back to v1's structure -- the best measured (~73 us vs 80-92 for all
// tiled/unrolled variants; depth experiments v4-v6 never changed the machine
// code shape, and Little's law says MLP wasn't the limit anyway) -- plus
// NON-TEMPORAL load AND store. Theory: both streams allocate in L2/L3;
// steady-state FETCH = 65.6 MB = half of x proves x+out (268 MB) thrash the
// 256 MB L3 every iteration, and every line pays allocate+evict overhead.
// The 6.7 TB/s poison fill at 9.6% occupancy looks like nt streaming stores;
// a same-shape float4 copy ubench does 6.29 TB/s. nt on both streams skips
// allocation entirely.
// Mechanism check: FETCH_SIZE should rise to ~131 MB (no L3 carryover).
using f4 = __attribute__((ext_vector_type(4))) float;

__global__ __launch_bounds__(256) void DiagonalDense_kernel(
    const f4* __restrict__ x,
    const f4* __restrict__ diag,
    f4* __restrict__ out,
    int n4) {
    int i = blockIdx.x * blockDim.x + threadIdx.x;
    if (i < n4) {
        f4 xv = __builtin_nontemporal_load(&x[i]);
        f4 dv = diag[i & 511];   // L1-resident broadcast; keep it cached (no nt)
        __builtin_nontemporal_store(xv * dv, &out[i]);
    }
}

extern "C" void kernel_launch(void* const* d_in, const int* in_sizes, int n_in,
                              void* d_out, int out_size, void* d_ws, size_t ws_size,
                              hipStream_t stream) {
    const f4* x    = (const f4*)d_in[0];   // 16384*2048 fp32
    const f4* diag = (const f4*)d_in[1];   // 2048 fp32
    f4* out        = (f4*)d_out;

    const int n  = out_size;       // 33,554,432 floats
    const int n4 = n / 4;          // 8,388,608 float4s (exactly divisible)
    const int block = 256;
    const int grid  = (n4 + block - 1) / block;   // 32768 blocks, exact

    DiagonalDense_kernel<<<grid, block, 0, stream>>>(x, diag, out, n4);
}